// Round 16
// baseline (215.515 us; speedup 1.0000x reference)
//
#include <hip/hip_runtime.h>

#define DI __device__ __forceinline__

typedef unsigned short u16t;
typedef u16t u16x4 __attribute__((ext_vector_type(4)));
typedef u16t u16x8 __attribute__((ext_vector_type(8)));
typedef short s16x8 __attribute__((ext_vector_type(8)));   // bf16 MFMA A/B frag
typedef float f32x4 __attribute__((ext_vector_type(4)));   // MFMA C/D frag

static constexpr int PLANE = 256 * 256 * 64;
static constexpr double PI = 3.14159265358979323846264338327950288;

DI float us2f(u16t u) {
  union { unsigned int i; float f; } v; v.i = ((unsigned int)u) << 16; return v.f;
}
DI u16t f2us(float f) {            // f32 -> bf16, RNE
  union { float f; unsigned int i; } v; v.f = f;
  unsigned int r = v.i + 0x7FFFu + ((v.i >> 16) & 1u);
  return (u16t)(r >> 16);
}
// fast gelu: x*sigmoid(1.59577x + 0.0713548x^3); |err| <= ~3e-3 abs.
DI float gelu(float x) {
  const float t = fmaf(0.0713548162726f * x * x, x, 1.5957691216057308f * x);
  const float e = __expf(-t);
  return x * __builtin_amdgcn_rcpf(1.0f + e);
}

// ------------- init: bf16 transform matrices + bf16 weights -----------------
__global__ void k_init(u16t* __restrict__ Mtf, u16t* __restrict__ Mti,
                       u16t* __restrict__ WqT, u16t* __restrict__ WkT,
                       u16t* __restrict__ WvT, u16t* __restrict__ pwT,
                       u16t* __restrict__ W1b, u16t* __restrict__ W2b,
                       const float* __restrict__ Wq, const float* __restrict__ Wk,
                       const float* __restrict__ Wv, const float* __restrict__ pw,
                       const float* __restrict__ c1a, const float* __restrict__ c2w)
{
  const int blk = blockIdx.x, t = threadIdx.x;
  if (blk < 256) {
    const int ko = blk, n = t;
    double af = PI * (2.0 * n + 1.0) * (double)ko / 512.0;
    Mtf[ko * 256 + n] = f2us((float)(2.0 * cos(af)));
    double wn = (n == 0) ? 0.5 : 1.0;
    double ai = PI * (2.0 * ko + 1.0) * (double)n / 512.0;
    Mti[ko * 256 + n] = f2us((float)(wn * cos(ai) / 256.0));
  } else {
    for (int i = 0; i < 16; ++i) {
      const int e = i * 256 + t;
      const int d = e >> 6, c = e & 63;
      WqT[e] = f2us(Wq[c * 64 + d]);
      WkT[e] = f2us(Wk[c * 64 + d]);
      WvT[e] = f2us(Wv[c * 64 + d]);
      pwT[e] = f2us(pw[c * 64 + d]);
      W1b[e] = f2us(c1a[e]);
      W2b[e] = f2us(c2w[e]);
    }
  }
}

// ---------------- 1-D transform, MFMA, 512 threads (8 waves) ----------------
template<bool INBF, bool OUTBF>
__global__ __launch_bounds__(512) void k_tmfma(const void* __restrict__ inv,
    void* __restrict__ outv, const u16t* __restrict__ Mt,
    const int s_other, const int s_row)
{
  __shared__ __align__(16) char sm[36864];     // XT[64][264] U OT[256][72]
  u16t (*XT)[264] = (u16t(*)[264])sm;
  u16t (*OT)[72]  = (u16t(*)[72])sm;
  const int t = threadIdx.x;
  const int b = blockIdx.x >> 8, other = blockIdx.x & 255;
  const size_t base = (size_t)b * PLANE + (size_t)other * (size_t)s_other;
  if constexpr (INBF) {
#pragma unroll
    for (int q = 0; q < 4; ++q) {
      const int id = q * 512 + t;
      const int n = id >> 3, c8 = (id & 7) * 8;
      u16x8 u = *(const u16x8*)((const u16t*)inv + base + (size_t)n * (size_t)s_row + c8);
#pragma unroll
      for (int j = 0; j < 8; ++j) XT[c8 + j][n] = u[j];
    }
  } else {
#pragma unroll
    for (int q = 0; q < 8; ++q) {
      const int id = q * 512 + t;
      const int n = id >> 4, c4 = (id & 15) * 4;
      float4 v = *(const float4*)((const float*)inv + base + (size_t)n * (size_t)s_row + c4);
      XT[c4 + 0][n] = f2us(v.x); XT[c4 + 1][n] = f2us(v.y);
      XT[c4 + 2][n] = f2us(v.z); XT[c4 + 3][n] = f2us(v.w);
    }
  }
  __syncthreads();
  const int w = t >> 6, l = t & 63;
  const int lr = l & 15, lg = l >> 4;
  f32x4 acc[4][2];
#pragma unroll
  for (int i = 0; i < 4; ++i)
#pragma unroll
    for (int j = 0; j < 2; ++j) acc[i][j] = (f32x4){0.f, 0.f, 0.f, 0.f};

  const u16t* mrow = Mt + (size_t)(w * 32 + lr) * 256 + lg * 8;
  s16x8 bnxt[2];
#pragma unroll
  for (int j = 0; j < 2; ++j) bnxt[j] = *(const s16x8*)(mrow + j * 4096);
  for (int ks = 0; ks < 8; ++ks) {
    s16x8 bcur[2];
#pragma unroll
    for (int j = 0; j < 2; ++j) bcur[j] = bnxt[j];
    if (ks < 7) {
#pragma unroll
      for (int j = 0; j < 2; ++j) bnxt[j] = *(const s16x8*)(mrow + (ks + 1) * 32 + j * 4096);
    }
    s16x8 afr[4];
#pragma unroll
    for (int i = 0; i < 4; ++i)
      afr[i] = *(const s16x8*)&XT[i * 16 + lr][ks * 32 + lg * 8];
#pragma unroll
    for (int i = 0; i < 4; ++i)
#pragma unroll
      for (int j = 0; j < 2; ++j)
        acc[i][j] = __builtin_amdgcn_mfma_f32_16x16x32_bf16(afr[i], bcur[j], acc[i][j], 0, 0, 0);
  }
  if constexpr (OUTBF) {
    __syncthreads();                 // all XT reads done; reuse LDS as OT
#pragma unroll
    for (int j = 0; j < 2; ++j)
#pragma unroll
      for (int i = 0; i < 4; ++i) {
        u16x4 u;
#pragma unroll
        for (int r = 0; r < 4; ++r) u[r] = f2us(acc[i][j][r]);
        *(u16x4*)&OT[w * 32 + j * 16 + lr][i * 16 + lg * 4] = u;
      }
    __syncthreads();
#pragma unroll
    for (int it = 0; it < 4; ++it) {
      const int id = it * 512 + t;
      const int ko = id >> 3, c8 = (id & 7) * 8;
      *(u16x8*)((u16t*)outv + base + (size_t)ko * (size_t)s_row + c8) =
          *(const u16x8*)&OT[ko][c8];
    }
  } else {
#pragma unroll
    for (int j = 0; j < 2; ++j)
#pragma unroll
      for (int i = 0; i < 4; ++i) {
        const size_t o = base + (size_t)(w * 32 + j * 16 + lr) * (size_t)s_row + i * 16 + lg * 4;
        *(f32x4*)((float*)outv + o) = acc[i][j];
      }
  }
}

// ------- fused DCT-H + conv1: 512 threads, single aliased LDS buffer --------
__global__ __launch_bounds__(512) void k_dcthc1(const u16t* __restrict__ inv,
    u16t* __restrict__ xdct, u16t* __restrict__ y1out,
    const u16t* __restrict__ Mt, const u16t* __restrict__ W1b)
{
  __shared__ __align__(16) char sm[36864];     // XT[64][264] U OT[256][72] U Y1
  u16t (*XT)[264] = (u16t(*)[264])sm;
  u16t (*OT)[72]  = (u16t(*)[72])sm;
  const int t = threadIdx.x;
  const int b = blockIdx.x >> 8, kw = blockIdx.x & 255;
  const size_t base = (size_t)b * PLANE + (size_t)kw * 64;
#pragma unroll
  for (int q = 0; q < 4; ++q) {
    const int id = q * 512 + t;
    const int n = id >> 3, c8 = (id & 7) * 8;
    u16x8 u = *(const u16x8*)(inv + base + (size_t)n * 16384 + c8);
#pragma unroll
    for (int j = 0; j < 8; ++j) XT[c8 + j][n] = u[j];
  }
  __syncthreads();
  const int w = t >> 6, l = t & 63;
  const int lr = l & 15, lg = l >> 4;
  f32x4 acc[4][2];
#pragma unroll
  for (int i = 0; i < 4; ++i)
#pragma unroll
    for (int j = 0; j < 2; ++j) acc[i][j] = (f32x4){0.f, 0.f, 0.f, 0.f};
  const u16t* mrow = Mt + (size_t)(w * 32 + lr) * 256 + lg * 8;
  for (int ks = 0; ks < 8; ++ks) {
    s16x8 afr[4];
#pragma unroll
    for (int i = 0; i < 4; ++i)
      afr[i] = *(const s16x8*)&XT[i * 16 + lr][ks * 32 + lg * 8];
#pragma unroll
    for (int j = 0; j < 2; ++j) {
      s16x8 bf = *(const s16x8*)(mrow + ks * 32 + j * 4096);
#pragma unroll
      for (int i = 0; i < 4; ++i)
        acc[i][j] = __builtin_amdgcn_mfma_f32_16x16x32_bf16(afr[i], bf, acc[i][j], 0, 0, 0);
    }
  }
  __syncthreads();                   // XT reads done -> reuse buffer as OT
#pragma unroll
  for (int j = 0; j < 2; ++j)
#pragma unroll
    for (int i = 0; i < 4; ++i) {
      u16x4 u;
#pragma unroll
      for (int r = 0; r < 4; ++r) u[r] = f2us(acc[i][j][r]);
      *(u16x4*)&OT[w * 32 + j * 16 + lr][i * 16 + lg * 4] = u;
    }
  __syncthreads();                   // OT (xdct tile) complete
#pragma unroll
  for (int it = 0; it < 4; ++it) {
    const int id = it * 512 + t;
    const int ko = id >> 3, c8 = (id & 7) * 8;
    *(u16x8*)(xdct + base + (size_t)ko * 16384 + c8) = *(const u16x8*)&OT[ko][c8];
  }
  s16x8 af2[4][2];
#pragma unroll
  for (int mt = 0; mt < 4; ++mt)
#pragma unroll
    for (int ks = 0; ks < 2; ++ks)
      af2[mt][ks] = *(const s16x8*)(W1b + (mt * 16 + lr) * 64 + ks * 32 + lg * 8);
  f32x4 acc2[4][2];
#pragma unroll
  for (int i = 0; i < 4; ++i)
#pragma unroll
    for (int j = 0; j < 2; ++j) acc2[i][j] = (f32x4){0.f, 0.f, 0.f, 0.f};
#pragma unroll
  for (int nt = 0; nt < 2; ++nt) {
    const int px = w * 32 + nt * 16 + lr;
#pragma unroll
    for (int ks = 0; ks < 2; ++ks) {
      s16x8 bf = *(const s16x8*)&OT[px][ks * 32 + lg * 8];
#pragma unroll
      for (int mt = 0; mt < 4; ++mt)
        acc2[mt][nt] = __builtin_amdgcn_mfma_f32_16x16x32_bf16(af2[mt][ks], bf, acc2[mt][nt], 0, 0, 0);
    }
  }
  __syncthreads();                   // OT reads done -> reuse buffer as Y1
#pragma unroll
  for (int mt = 0; mt < 4; ++mt)
#pragma unroll
    for (int nt = 0; nt < 2; ++nt) {
      const int px = w * 32 + nt * 16 + lr;
      u16x4 u;
#pragma unroll
      for (int r = 0; r < 4; ++r) u[r] = f2us(gelu(acc2[mt][nt][r]));
      *(u16x4*)&OT[px][mt * 16 + lg * 4] = u;
    }
  __syncthreads();
#pragma unroll
  for (int it = 0; it < 4; ++it) {
    const int id = it * 512 + t;
    const int kh = id >> 3, c8 = (id & 7) * 8;
    *(u16x8*)(y1out + base + (size_t)kh * 16384 + c8) = *(const u16x8*)&OT[kh][c8];
  }
}

// ---------------- attention branch: 30 KB LDS (VM aliases QT) ---------------
DI size_t gaddr(int nb, int mm) {
  const int b = nb >> 10, r = nb & 1023, bh = r >> 5, bw = r & 31;
  const int i = mm >> 3, j = mm & 7;
  return ((size_t)((b * 256 + bh * 8 + i) * 256 + bw * 8 + j)) * 64;
}

__global__ __launch_bounds__(256, 5) void k_attn(const u16t* __restrict__ xdct,
    u16t* __restrict__ xlow, const u16t* __restrict__ WqT,
    const u16t* __restrict__ WkT, const u16t* __restrict__ WvT,
    const u16t* __restrict__ pwT, const float* __restrict__ resc,
    const float* __restrict__ pb)
{
  __shared__ __align__(16) u16t Xs[64][72], QT[64][72], KT[64][72];
  __shared__ __align__(16) u16t PSb[4][16][24];
  u16t (*X1)[72] = Xs;               // alias: Xs reads fenced before X1 writes
  u16t (*VM)[72] = QT;               // alias: QT dead after S^T (barrier-fenced)
  const int t = threadIdx.x, w = t >> 6, l = t & 63;
  const int lr = l & 15, lg = l >> 4;
  const int nb = blockIdx.x;
#pragma unroll
  for (int q = 0; q < 2; ++q) {
    const int id = q * 256 + t, px = id >> 3, c8 = (id & 7) * 8;
    *(u16x8*)&Xs[px][c8] = *(const u16x8*)(xdct + gaddr(nb, px) + c8);
  }
  __syncthreads();
  s16x8 afr[4][2];
#pragma unroll
  for (int mt = 0; mt < 4; ++mt)
#pragma unroll
    for (int ks = 0; ks < 2; ++ks)
      afr[mt][ks] = *(const s16x8*)&Xs[mt * 16 + lr][ks * 32 + lg * 8];
  __syncthreads();                   // all Xs reads done -> X1 may overwrite

  auto qkv = [&](const u16t* __restrict__ WT, u16t (&DST)[64][72]) {
    f32x4 acc[4];
#pragma unroll
    for (int mt = 0; mt < 4; ++mt) acc[mt] = (f32x4){0.f, 0.f, 0.f, 0.f};
#pragma unroll
    for (int ks = 0; ks < 2; ++ks) {
      s16x8 bf = *(const s16x8*)(WT + (w * 16 + lr) * 64 + ks * 32 + lg * 8);
#pragma unroll
      for (int mt = 0; mt < 4; ++mt)
        acc[mt] = __builtin_amdgcn_mfma_f32_16x16x32_bf16(afr[mt][ks], bf, acc[mt], 0, 0, 0);
    }
    float ss = 0.f;
#pragma unroll
    for (int mt = 0; mt < 4; ++mt)
#pragma unroll
      for (int r = 0; r < 4; ++r) ss = fmaf(acc[mt][r], acc[mt][r], ss);
    ss += __shfl_xor(ss, 16); ss += __shfl_xor(ss, 32);
    const float inv = 1.0f / fmaxf(sqrtf(ss), 1e-12f);
#pragma unroll
    for (int mt = 0; mt < 4; ++mt) {
      u16x4 u;
#pragma unroll
      for (int r = 0; r < 4; ++r) u[r] = f2us(acc[mt][r] * inv);
      *(u16x4*)&DST[w * 16 + lr][mt * 16 + lg * 4] = u;
    }
  };
  qkv(WqT, QT);
  qkv(WkT, KT);
  f32x4 vacc[4];
#pragma unroll
  for (int mt = 0; mt < 4; ++mt) vacc[mt] = (f32x4){0.f, 0.f, 0.f, 0.f};
#pragma unroll
  for (int ks = 0; ks < 2; ++ks) {
    s16x8 bf = *(const s16x8*)(WvT + (w * 16 + lr) * 64 + ks * 32 + lg * 8);
#pragma unroll
    for (int mt = 0; mt < 4; ++mt)
      vacc[mt] = __builtin_amdgcn_mfma_f32_16x16x32_bf16(afr[mt][ks], bf, vacc[mt], 0, 0, 0);
  }

  f32x4 s = (f32x4){0.f, 0.f, 0.f, 0.f};
#pragma unroll
  for (int ks = 0; ks < 2; ++ks) {
    s16x8 ak = *(const s16x8*)&KT[w * 16 + lr][ks * 32 + lg * 8];
    s16x8 bq = *(const s16x8*)&QT[w * 16 + lr][ks * 32 + lg * 8];
    s = __builtin_amdgcn_mfma_f32_16x16x32_bf16(ak, bq, s, 0, 0, 0);
  }
  const float rs = resc[w];
  float a[4];
#pragma unroll
  for (int r = 0; r < 4; ++r) a[r] = s[r] * rs;
  float mx = fmaxf(fmaxf(a[0], a[1]), fmaxf(a[2], a[3]));
  mx = fmaxf(mx, __shfl_xor(mx, 16)); mx = fmaxf(mx, __shfl_xor(mx, 32));
  float sm = 0.f;
#pragma unroll
  for (int r = 0; r < 4; ++r) { a[r] = expf(a[r] - mx); sm += a[r]; }
  sm += __shfl_xor(sm, 16); sm += __shfl_xor(sm, 32);
  const float sinv = 1.0f / sm;
  u16x4 pp;
#pragma unroll
  for (int r = 0; r < 4; ++r) pp[r] = f2us(a[r] * sinv);
  *(u16x4*)&PSb[w][lr][lg * 4] = pp;     // P[d=lr][e=lg*4+r]
  __syncthreads();                   // all S^T reads of QT done -> VM may overwrite
#pragma unroll
  for (int mt = 0; mt < 4; ++mt)
#pragma unroll
    for (int r = 0; r < 4; ++r)
      VM[mt * 16 + lg * 4 + r][w * 16 + lr] = f2us(vacc[mt][r]);   // VM[m][d]
  __syncthreads();                   // VM complete

  const s16x8 zf = (s16x8){0, 0, 0, 0, 0, 0, 0, 0};
  s16x8 pa = zf;
  if (lg < 2) pa = *(const s16x8*)&PSb[w][lr][lg * 8];
#pragma unroll
  for (int mt = 0; mt < 4; ++mt) {
    s16x8 bv = zf;
    if (lg < 2) bv = *(const s16x8*)&VM[mt * 16 + lr][w * 16 + lg * 8];
    f32x4 o = __builtin_amdgcn_mfma_f32_16x16x32_bf16(pa, bv, (f32x4){0.f, 0.f, 0.f, 0.f}, 0, 0, 0);
    u16x4 u;
#pragma unroll
    for (int r = 0; r < 4; ++r) u[r] = f2us(o[r]);
    *(u16x4*)&X1[mt * 16 + lr][w * 16 + lg * 4] = u;
  }
  __syncthreads();

  f32x4 pacc[4];
#pragma unroll
  for (int mt = 0; mt < 4; ++mt) pacc[mt] = (f32x4){0.f, 0.f, 0.f, 0.f};
#pragma unroll
  for (int ks = 0; ks < 2; ++ks) {
    s16x8 bx = *(const s16x8*)&X1[w * 16 + lr][ks * 32 + lg * 8];
#pragma unroll
    for (int mt = 0; mt < 4; ++mt) {
      s16x8 ap = *(const s16x8*)(pwT + (mt * 16 + lr) * 64 + ks * 32 + lg * 8);
      pacc[mt] = __builtin_amdgcn_mfma_f32_16x16x32_bf16(ap, bx, pacc[mt], 0, 0, 0);
    }
  }
#pragma unroll
  for (int mt = 0; mt < 4; ++mt) {
    const float4 bias = *(const float4*)(pb + mt * 16 + lg * 4);
    u16x4 u;
    u[0] = f2us(pacc[mt][0] + bias.x); u[1] = f2us(pacc[mt][1] + bias.y);
    u[2] = f2us(pacc[mt][2] + bias.z); u[3] = f2us(pacc[mt][3] + bias.w);
    *(u16x4*)&X1[w * 16 + lr][mt * 16 + lg * 4] = u;
  }
  __syncthreads();
#pragma unroll
  for (int it = 0; it < 2; ++it) {
    const int id = it * 256 + t;
    const int mm = id >> 3, c8 = (id & 7) * 8;
    *(u16x8*)(xlow + gaddr(nb, mm) + c8) = *(const u16x8*)&X1[mm][c8];
  }
}

// ------- fused depthwise + c2 GEMM + combine + IDCT-W (512 threads) ---------
// Phase A uses column-rolling tap reuse: thread owns 4 consecutive px, sweeps
// 6 y1 columns once (18 loads, 144 converts vs 36/288 in the 4-pass form).
__global__ __launch_bounds__(512) void k_dwc2i(const u16t* __restrict__ y1,
    u16t* __restrict__ xio, const u16t* __restrict__ xlow,
    const u16t* __restrict__ W2b, const u16t* __restrict__ Mti,
    const float* __restrict__ dwg, const float* __restrict__ coef)
{
  __shared__ __align__(16) char smu[36864];    // OT[256][72] U XT[64][264]
  u16t (*OT)[72]  = (u16t(*)[72])smu;
  u16t (*XT)[264] = (u16t(*)[264])smu;
  __shared__ float dws[64][9];
  const int t = threadIdx.x, w = t >> 6, l = t & 63;
  const int lr = l & 15, lg = l >> 4;
  const int bid = blockIdx.x;
  const int blk = (bid & 7) * 128 + (bid >> 3);   // XCD-aware row swizzle
  const int b = blk >> 8, py = blk & 255;
  const size_t ebase = (size_t)blk * 16384;
  const int pb0 = py * 256;
  for (int e = t; e < 576; e += 512) dws[e / 9][e % 9] = dwg[e];
  __syncthreads();
  // ---- phase A: depthwise 3x3 via column sweep + gelu + residual -> OT ----
  {
    const int pxo = (t >> 3) * 4;           // 4 consecutive px per thread
    const int c8 = (t & 7) * 8;
    float acc[4][8];
#pragma unroll
    for (int k = 0; k < 4; ++k)
#pragma unroll
      for (int r = 0; r < 8; ++r) acc[k][r] = 0.f;
#pragma unroll
    for (int o = 0; o < 6; ++o) {
      const int rx = pxo - 1 + o;
      const bool colok = (unsigned)rx < 256u;
      float cv[3][8];
#pragma unroll
      for (int dy = 0; dy < 3; ++dy) {
        const int ry = py + dy - 1;
        u16x8 v = {0, 0, 0, 0, 0, 0, 0, 0};
        if (colok && (unsigned)ry < 256u)
          v = *(const u16x8*)(y1 + ((size_t)((b * 256 + ry) * 256 + rx)) * 64 + c8);
#pragma unroll
        for (int r = 0; r < 8; ++r) cv[dy][r] = us2f(v[r]);
      }
      const int klo = (o - 2 < 0) ? 0 : o - 2;
      const int khi = (o < 3) ? o : 3;
#pragma unroll
      for (int k = 0; k < 4; ++k) {
        if (k < klo || k > khi) continue;   // folds per unrolled o
        const int dx = o - k;
#pragma unroll
        for (int dy = 0; dy < 3; ++dy) {
          const int j = dy * 3 + dx;
#pragma unroll
          for (int r = 0; r < 8; ++r)
            acc[k][r] = fmaf(cv[dy][r], dws[c8 + r][j], acc[k][r]);
        }
      }
    }
#pragma unroll
    for (int k = 0; k < 4; ++k) {
      const int px = pxo + k;
      const u16x8 x = *(const u16x8*)(xio + ebase + (size_t)px * 64 + c8);
      u16x8 ov;
#pragma unroll
      for (int r = 0; r < 8; ++r) ov[r] = f2us(gelu(acc[k][r]) + us2f(x[r]));
      *(u16x8*)&OT[px][c8] = ov;
    }
  }
  __syncthreads();
  // ---- phase B: c2 GEMM (wave w owns px tile [w*32, w*32+32)) ----
  s16x8 af[4][2];
#pragma unroll
  for (int mt = 0; mt < 4; ++mt)
#pragma unroll
    for (int ks = 0; ks < 2; ++ks)
      af[mt][ks] = *(const s16x8*)(W2b + (mt * 16 + lr) * 64 + ks * 32 + lg * 8);
  f32x4 acc[4][2];
#pragma unroll
  for (int i = 0; i < 4; ++i)
#pragma unroll
    for (int j = 0; j < 2; ++j) acc[i][j] = (f32x4){0.f, 0.f, 0.f, 0.f};
#pragma unroll
  for (int nt = 0; nt < 2; ++nt) {
    const int px = w * 32 + nt * 16 + lr;
#pragma unroll
    for (int ks = 0; ks < 2; ++ks) {
      s16x8 bf = *(const s16x8*)&OT[px][ks * 32 + lg * 8];
#pragma unroll
      for (int mt = 0; mt < 4; ++mt)
        acc[mt][nt] = __builtin_amdgcn_mfma_f32_16x16x32_bf16(af[mt][ks], bf, acc[mt][nt], 0, 0, 0);
    }
  }
  u16x4 cmb[2][4];                   // combined row values, bf16, in regs
#pragma unroll
  for (int nt = 0; nt < 2; ++nt) {
    const int px = w * 32 + nt * 16 + lr;
    const float cf = coef[pb0 + px];
    const size_t gb = ebase + (size_t)px * 64;
#pragma unroll
    for (int mt = 0; mt < 4; ++mt) {
      const int c0 = mt * 16 + lg * 4;
      const u16x4 xd = *(const u16x4*)(xio + gb + c0);      // L1/L2-hot
      const u16x4 xl = *(const u16x4*)(xlow + gb + c0);
      const u16x4 xr = *(const u16x4*)&OT[px][c0];
      u16x4 o;
#pragma unroll
      for (int r = 0; r < 4; ++r) {
        const float xh = gelu(acc[mt][nt][r]) + us2f(xr[r]);
        o[r] = f2us(cf * us2f(xl[r]) + (1.0f - cf) * xh + us2f(xd[r]));
      }
      cmb[nt][mt] = o;
    }
  }
  __syncthreads();                   // ALL OT reads done -> overwrite as XT
#pragma unroll
  for (int nt = 0; nt < 2; ++nt) {
    const int px = w * 32 + nt * 16 + lr;
#pragma unroll
    for (int mt = 0; mt < 4; ++mt) {
      const int c0 = mt * 16 + lg * 4;
#pragma unroll
      for (int r = 0; r < 4; ++r) XT[c0 + r][px] = cmb[nt][mt][r];
    }
  }
  __syncthreads();                   // XT complete
  // ---- phase C: IDCT-W (wave w owns ko tile [w*32, w*32+32)) ----
  f32x4 acc2[4][2];
#pragma unroll
  for (int i = 0; i < 4; ++i)
#pragma unroll
    for (int j = 0; j < 2; ++j) acc2[i][j] = (f32x4){0.f, 0.f, 0.f, 0.f};
  const u16t* mrow = Mti + (size_t)(w * 32 + lr) * 256 + lg * 8;
  for (int ks = 0; ks < 8; ++ks) {
    s16x8 afr[4];
#pragma unroll
    for (int i = 0; i < 4; ++i)
      afr[i] = *(const s16x8*)&XT[i * 16 + lr][ks * 32 + lg * 8];
#pragma unroll
    for (int j = 0; j < 2; ++j) {
      s16x8 bf = *(const s16x8*)(mrow + ks * 32 + j * 4096);
#pragma unroll
      for (int i = 0; i < 4; ++i)
        acc2[i][j] = __builtin_amdgcn_mfma_f32_16x16x32_bf16(afr[i], bf, acc2[i][j], 0, 0, 0);
    }
  }
  __syncthreads();                   // XT reads done -> reuse buffer as OT
#pragma unroll
  for (int j = 0; j < 2; ++j)
#pragma unroll
    for (int i = 0; i < 4; ++i) {
      u16x4 u;
#pragma unroll
      for (int r = 0; r < 4; ++r) u[r] = f2us(acc2[i][j][r]);
      *(u16x4*)&OT[w * 32 + j * 16 + lr][i * 16 + lg * 4] = u;
    }
  __syncthreads();
#pragma unroll
  for (int it = 0; it < 4; ++it) {
    const int id = it * 512 + t;
    const int ko = id >> 3, c8 = (id & 7) * 8;
    *(u16x8*)(xio + ebase + (size_t)ko * 64 + c8) = *(const u16x8*)&OT[ko][c8];
  }
}

// ----------------------------------------------------------------------------
extern "C" void kernel_launch(void* const* d_in, const int* in_sizes, int n_in,
                              void* d_out, int out_size, void* d_ws, size_t ws_size,
                              hipStream_t stream) {
  const float* x_input = (const float*)d_in[0];
  const float* Wq      = (const float*)d_in[1];
  const float* Wk      = (const float*)d_in[2];
  const float* Wv      = (const float*)d_in[3];
  const float* resc    = (const float*)d_in[4];
  const float* proj_w  = (const float*)d_in[5];
  const float* proj_b  = (const float*)d_in[6];
  const float* c1a_w   = (const float*)d_in[7];
  const float* c1b_w   = (const float*)d_in[8];
  const float* c2_w    = (const float*)d_in[9];
  const float* coef    = (const float*)d_in[10];
  float* out = (float*)d_out;

  char* ws = (char*)d_ws;
  u16t* A   = (u16t*)ws;                       // 33.5 MB
  u16t* Bb  = (u16t*)(ws + 33554432);          // 33.5 MB
  u16t* Mtf = (u16t*)(ws + 67108864);
  u16t* Mti = Mtf + 65536;
  u16t* WqT = Mti + 65536;
  u16t* WkT = WqT + 4096;
  u16t* WvT = WkT + 4096;
  u16t* pwT = WvT + 4096;
  u16t* W1b = pwT + 4096;
  u16t* W2b = W1b + 4096;
  u16t* xlow = (u16t*)d_out;                   // bf16, first half of d_out

  k_init<<<dim3(257), dim3(256), 0, stream>>>(Mtf, Mti, WqT, WkT, WvT, pwT, W1b, W2b,
                                              Wq, Wk, Wv, proj_w, c1a_w, c2_w);
  // DCT along W: x -> A
  k_tmfma<false, true><<<dim3(1024), dim3(512), 0, stream>>>(x_input, A, Mtf, 16384, 64);
  // fused DCT-H + conv1: A -> Bb (xdct), A (y1, in place)
  k_dcthc1<<<dim3(1024), dim3(512), 0, stream>>>(A, Bb, A, Mtf, W1b);
  // attention branch: xdct -> x_low
  k_attn<<<dim3(4096), dim3(256), 0, stream>>>(Bb, xlow, WqT, WkT, WvT, pwT, resc, proj_b);
  // fused depthwise + c2 + combine + IDCT-W: (A=y1, Bb=xdct, xlow) -> Bb in place
  k_dwc2i<<<dim3(1024), dim3(512), 0, stream>>>(A, Bb, xlow, W2b, Mti, c1b_w, coef);
  // IDCT along H: Bb -> out (f32, final NHWC)
  k_tmfma<true, false><<<dim3(1024), dim3(512), 0, stream>>>(Bb, out, Mti, 64, 16384);
}

// Round 17
// 208.625 us; speedup vs baseline: 1.0330x; 1.0330x over previous
//
#include <hip/hip_runtime.h>

#define DI __device__ __forceinline__

typedef unsigned short u16t;
typedef u16t u16x4 __attribute__((ext_vector_type(4)));
typedef u16t u16x8 __attribute__((ext_vector_type(8)));
typedef short s16x8 __attribute__((ext_vector_type(8)));   // bf16 MFMA A/B frag
typedef float f32x4 __attribute__((ext_vector_type(4)));   // MFMA C/D frag

static constexpr int PLANE = 256 * 256 * 64;
static constexpr double PI = 3.14159265358979323846264338327950288;

DI float us2f(u16t u) {
  union { unsigned int i; float f; } v; v.i = ((unsigned int)u) << 16; return v.f;
}
DI u16t f2us(float f) {            // f32 -> bf16, RNE
  union { float f; unsigned int i; } v; v.f = f;
  unsigned int r = v.i + 0x7FFFu + ((v.i >> 16) & 1u);
  return (u16t)(r >> 16);
}
// fast gelu: x*sigmoid(1.59577x + 0.0713548x^3); |err| <= ~3e-3 abs.
DI float gelu(float x) {
  const float t = fmaf(0.0713548162726f * x * x, x, 1.5957691216057308f * x);
  const float e = __expf(-t);
  return x * __builtin_amdgcn_rcpf(1.0f + e);
}

// ------------- init: bf16 transform matrices + bf16 weights -----------------
__global__ void k_init(u16t* __restrict__ Mtf, u16t* __restrict__ Mti,
                       u16t* __restrict__ WqT, u16t* __restrict__ WkT,
                       u16t* __restrict__ WvT, u16t* __restrict__ pwT,
                       u16t* __restrict__ W1b, u16t* __restrict__ W2b,
                       const float* __restrict__ Wq, const float* __restrict__ Wk,
                       const float* __restrict__ Wv, const float* __restrict__ pw,
                       const float* __restrict__ c1a, const float* __restrict__ c2w)
{
  const int blk = blockIdx.x, t = threadIdx.x;
  if (blk < 256) {
    const int ko = blk, n = t;
    double af = PI * (2.0 * n + 1.0) * (double)ko / 512.0;
    Mtf[ko * 256 + n] = f2us((float)(2.0 * cos(af)));
    double wn = (n == 0) ? 0.5 : 1.0;
    double ai = PI * (2.0 * ko + 1.0) * (double)n / 512.0;
    Mti[ko * 256 + n] = f2us((float)(wn * cos(ai) / 256.0));
  } else {
    for (int i = 0; i < 16; ++i) {
      const int e = i * 256 + t;
      const int d = e >> 6, c = e & 63;
      WqT[e] = f2us(Wq[c * 64 + d]);
      WkT[e] = f2us(Wk[c * 64 + d]);
      WvT[e] = f2us(Wv[c * 64 + d]);
      pwT[e] = f2us(pw[c * 64 + d]);
      W1b[e] = f2us(c1a[e]);
      W2b[e] = f2us(c2w[e]);
    }
  }
}

// ---------------- 1-D transform, MFMA, 512 threads (8 waves) ----------------
template<bool INBF, bool OUTBF>
__global__ __launch_bounds__(512) void k_tmfma(const void* __restrict__ inv,
    void* __restrict__ outv, const u16t* __restrict__ Mt,
    const int s_other, const int s_row)
{
  __shared__ __align__(16) char sm[36864];     // XT[64][264] U OT[256][72]
  u16t (*XT)[264] = (u16t(*)[264])sm;
  u16t (*OT)[72]  = (u16t(*)[72])sm;
  const int t = threadIdx.x;
  const int b = blockIdx.x >> 8, other = blockIdx.x & 255;
  const size_t base = (size_t)b * PLANE + (size_t)other * (size_t)s_other;
  if constexpr (INBF) {
#pragma unroll
    for (int q = 0; q < 4; ++q) {
      const int id = q * 512 + t;
      const int n = id >> 3, c8 = (id & 7) * 8;
      u16x8 u = *(const u16x8*)((const u16t*)inv + base + (size_t)n * (size_t)s_row + c8);
#pragma unroll
      for (int j = 0; j < 8; ++j) XT[c8 + j][n] = u[j];
    }
  } else {
#pragma unroll
    for (int q = 0; q < 8; ++q) {
      const int id = q * 512 + t;
      const int n = id >> 4, c4 = (id & 15) * 4;
      float4 v = *(const float4*)((const float*)inv + base + (size_t)n * (size_t)s_row + c4);
      XT[c4 + 0][n] = f2us(v.x); XT[c4 + 1][n] = f2us(v.y);
      XT[c4 + 2][n] = f2us(v.z); XT[c4 + 3][n] = f2us(v.w);
    }
  }
  __syncthreads();
  const int w = t >> 6, l = t & 63;
  const int lr = l & 15, lg = l >> 4;
  f32x4 acc[4][2];
#pragma unroll
  for (int i = 0; i < 4; ++i)
#pragma unroll
    for (int j = 0; j < 2; ++j) acc[i][j] = (f32x4){0.f, 0.f, 0.f, 0.f};

  const u16t* mrow = Mt + (size_t)(w * 32 + lr) * 256 + lg * 8;
  s16x8 bnxt[2];
#pragma unroll
  for (int j = 0; j < 2; ++j) bnxt[j] = *(const s16x8*)(mrow + j * 4096);
  for (int ks = 0; ks < 8; ++ks) {
    s16x8 bcur[2];
#pragma unroll
    for (int j = 0; j < 2; ++j) bcur[j] = bnxt[j];
    if (ks < 7) {
#pragma unroll
      for (int j = 0; j < 2; ++j) bnxt[j] = *(const s16x8*)(mrow + (ks + 1) * 32 + j * 4096);
    }
    s16x8 afr[4];
#pragma unroll
    for (int i = 0; i < 4; ++i)
      afr[i] = *(const s16x8*)&XT[i * 16 + lr][ks * 32 + lg * 8];
#pragma unroll
    for (int i = 0; i < 4; ++i)
#pragma unroll
      for (int j = 0; j < 2; ++j)
        acc[i][j] = __builtin_amdgcn_mfma_f32_16x16x32_bf16(afr[i], bcur[j], acc[i][j], 0, 0, 0);
  }
  if constexpr (OUTBF) {
    __syncthreads();                 // all XT reads done; reuse LDS as OT
#pragma unroll
    for (int j = 0; j < 2; ++j)
#pragma unroll
      for (int i = 0; i < 4; ++i) {
        u16x4 u;
#pragma unroll
        for (int r = 0; r < 4; ++r) u[r] = f2us(acc[i][j][r]);
        *(u16x4*)&OT[w * 32 + j * 16 + lr][i * 16 + lg * 4] = u;
      }
    __syncthreads();
#pragma unroll
    for (int it = 0; it < 4; ++it) {
      const int id = it * 512 + t;
      const int ko = id >> 3, c8 = (id & 7) * 8;
      *(u16x8*)((u16t*)outv + base + (size_t)ko * (size_t)s_row + c8) =
          *(const u16x8*)&OT[ko][c8];
    }
  } else {
#pragma unroll
    for (int j = 0; j < 2; ++j)
#pragma unroll
      for (int i = 0; i < 4; ++i) {
        const size_t o = base + (size_t)(w * 32 + j * 16 + lr) * (size_t)s_row + i * 16 + lg * 4;
        *(f32x4*)((float*)outv + o) = acc[i][j];
      }
  }
}

// ------- fused DCT-H + conv1: 512 threads, single aliased LDS buffer --------
__global__ __launch_bounds__(512) void k_dcthc1(const u16t* __restrict__ inv,
    u16t* __restrict__ xdct, u16t* __restrict__ y1out,
    const u16t* __restrict__ Mt, const u16t* __restrict__ W1b)
{
  __shared__ __align__(16) char sm[36864];     // XT[64][264] U OT[256][72] U Y1
  u16t (*XT)[264] = (u16t(*)[264])sm;
  u16t (*OT)[72]  = (u16t(*)[72])sm;
  const int t = threadIdx.x;
  const int b = blockIdx.x >> 8, kw = blockIdx.x & 255;
  const size_t base = (size_t)b * PLANE + (size_t)kw * 64;
#pragma unroll
  for (int q = 0; q < 4; ++q) {
    const int id = q * 512 + t;
    const int n = id >> 3, c8 = (id & 7) * 8;
    u16x8 u = *(const u16x8*)(inv + base + (size_t)n * 16384 + c8);
#pragma unroll
    for (int j = 0; j < 8; ++j) XT[c8 + j][n] = u[j];
  }
  __syncthreads();
  const int w = t >> 6, l = t & 63;
  const int lr = l & 15, lg = l >> 4;
  f32x4 acc[4][2];
#pragma unroll
  for (int i = 0; i < 4; ++i)
#pragma unroll
    for (int j = 0; j < 2; ++j) acc[i][j] = (f32x4){0.f, 0.f, 0.f, 0.f};
  const u16t* mrow = Mt + (size_t)(w * 32 + lr) * 256 + lg * 8;
  for (int ks = 0; ks < 8; ++ks) {
    s16x8 afr[4];
#pragma unroll
    for (int i = 0; i < 4; ++i)
      afr[i] = *(const s16x8*)&XT[i * 16 + lr][ks * 32 + lg * 8];
#pragma unroll
    for (int j = 0; j < 2; ++j) {
      s16x8 bf = *(const s16x8*)(mrow + ks * 32 + j * 4096);
#pragma unroll
      for (int i = 0; i < 4; ++i)
        acc[i][j] = __builtin_amdgcn_mfma_f32_16x16x32_bf16(afr[i], bf, acc[i][j], 0, 0, 0);
    }
  }
  __syncthreads();                   // XT reads done -> reuse buffer as OT
#pragma unroll
  for (int j = 0; j < 2; ++j)
#pragma unroll
    for (int i = 0; i < 4; ++i) {
      u16x4 u;
#pragma unroll
      for (int r = 0; r < 4; ++r) u[r] = f2us(acc[i][j][r]);
      *(u16x4*)&OT[w * 32 + j * 16 + lr][i * 16 + lg * 4] = u;
    }
  __syncthreads();                   // OT (xdct tile) complete
#pragma unroll
  for (int it = 0; it < 4; ++it) {
    const int id = it * 512 + t;
    const int ko = id >> 3, c8 = (id & 7) * 8;
    *(u16x8*)(xdct + base + (size_t)ko * 16384 + c8) = *(const u16x8*)&OT[ko][c8];
  }
  s16x8 af2[4][2];
#pragma unroll
  for (int mt = 0; mt < 4; ++mt)
#pragma unroll
    for (int ks = 0; ks < 2; ++ks)
      af2[mt][ks] = *(const s16x8*)(W1b + (mt * 16 + lr) * 64 + ks * 32 + lg * 8);
  f32x4 acc2[4][2];
#pragma unroll
  for (int i = 0; i < 4; ++i)
#pragma unroll
    for (int j = 0; j < 2; ++j) acc2[i][j] = (f32x4){0.f, 0.f, 0.f, 0.f};
#pragma unroll
  for (int nt = 0; nt < 2; ++nt) {
    const int px = w * 32 + nt * 16 + lr;
#pragma unroll
    for (int ks = 0; ks < 2; ++ks) {
      s16x8 bf = *(const s16x8*)&OT[px][ks * 32 + lg * 8];
#pragma unroll
      for (int mt = 0; mt < 4; ++mt)
        acc2[mt][nt] = __builtin_amdgcn_mfma_f32_16x16x32_bf16(af2[mt][ks], bf, acc2[mt][nt], 0, 0, 0);
    }
  }
  __syncthreads();                   // OT reads done -> reuse buffer as Y1
#pragma unroll
  for (int mt = 0; mt < 4; ++mt)
#pragma unroll
    for (int nt = 0; nt < 2; ++nt) {
      const int px = w * 32 + nt * 16 + lr;
      u16x4 u;
#pragma unroll
      for (int r = 0; r < 4; ++r) u[r] = f2us(gelu(acc2[mt][nt][r]));
      *(u16x4*)&OT[px][mt * 16 + lg * 4] = u;
    }
  __syncthreads();
#pragma unroll
  for (int it = 0; it < 4; ++it) {
    const int id = it * 512 + t;
    const int kh = id >> 3, c8 = (id & 7) * 8;
    *(u16x8*)(y1out + base + (size_t)kh * 16384 + c8) = *(const u16x8*)&OT[kh][c8];
  }
}

// ---------------- attention branch: 30 KB LDS (VM aliases QT) ---------------
DI size_t gaddr(int nb, int mm) {
  const int b = nb >> 10, r = nb & 1023, bh = r >> 5, bw = r & 31;
  const int i = mm >> 3, j = mm & 7;
  return ((size_t)((b * 256 + bh * 8 + i) * 256 + bw * 8 + j)) * 64;
}

__global__ __launch_bounds__(256, 5) void k_attn(const u16t* __restrict__ xdct,
    u16t* __restrict__ xlow, const u16t* __restrict__ WqT,
    const u16t* __restrict__ WkT, const u16t* __restrict__ WvT,
    const u16t* __restrict__ pwT, const float* __restrict__ resc,
    const float* __restrict__ pb)
{
  __shared__ __align__(16) u16t Xs[64][72], QT[64][72], KT[64][72];
  __shared__ __align__(16) u16t PSb[4][16][24];
  u16t (*X1)[72] = Xs;               // alias: Xs reads fenced before X1 writes
  u16t (*VM)[72] = QT;               // alias: QT dead after S^T (barrier-fenced)
  const int t = threadIdx.x, w = t >> 6, l = t & 63;
  const int lr = l & 15, lg = l >> 4;
  const int nb = blockIdx.x;
#pragma unroll
  for (int q = 0; q < 2; ++q) {
    const int id = q * 256 + t, px = id >> 3, c8 = (id & 7) * 8;
    *(u16x8*)&Xs[px][c8] = *(const u16x8*)(xdct + gaddr(nb, px) + c8);
  }
  __syncthreads();
  s16x8 afr[4][2];
#pragma unroll
  for (int mt = 0; mt < 4; ++mt)
#pragma unroll
    for (int ks = 0; ks < 2; ++ks)
      afr[mt][ks] = *(const s16x8*)&Xs[mt * 16 + lr][ks * 32 + lg * 8];
  __syncthreads();                   // all Xs reads done -> X1 may overwrite

  auto qkv = [&](const u16t* __restrict__ WT, u16t (&DST)[64][72]) {
    f32x4 acc[4];
#pragma unroll
    for (int mt = 0; mt < 4; ++mt) acc[mt] = (f32x4){0.f, 0.f, 0.f, 0.f};
#pragma unroll
    for (int ks = 0; ks < 2; ++ks) {
      s16x8 bf = *(const s16x8*)(WT + (w * 16 + lr) * 64 + ks * 32 + lg * 8);
#pragma unroll
      for (int mt = 0; mt < 4; ++mt)
        acc[mt] = __builtin_amdgcn_mfma_f32_16x16x32_bf16(afr[mt][ks], bf, acc[mt], 0, 0, 0);
    }
    float ss = 0.f;
#pragma unroll
    for (int mt = 0; mt < 4; ++mt)
#pragma unroll
      for (int r = 0; r < 4; ++r) ss = fmaf(acc[mt][r], acc[mt][r], ss);
    ss += __shfl_xor(ss, 16); ss += __shfl_xor(ss, 32);
    const float inv = 1.0f / fmaxf(sqrtf(ss), 1e-12f);
#pragma unroll
    for (int mt = 0; mt < 4; ++mt) {
      u16x4 u;
#pragma unroll
      for (int r = 0; r < 4; ++r) u[r] = f2us(acc[mt][r] * inv);
      *(u16x4*)&DST[w * 16 + lr][mt * 16 + lg * 4] = u;
    }
  };
  qkv(WqT, QT);
  qkv(WkT, KT);
  f32x4 vacc[4];
#pragma unroll
  for (int mt = 0; mt < 4; ++mt) vacc[mt] = (f32x4){0.f, 0.f, 0.f, 0.f};
#pragma unroll
  for (int ks = 0; ks < 2; ++ks) {
    s16x8 bf = *(const s16x8*)(WvT + (w * 16 + lr) * 64 + ks * 32 + lg * 8);
#pragma unroll
    for (int mt = 0; mt < 4; ++mt)
      vacc[mt] = __builtin_amdgcn_mfma_f32_16x16x32_bf16(afr[mt][ks], bf, vacc[mt], 0, 0, 0);
  }

  f32x4 s = (f32x4){0.f, 0.f, 0.f, 0.f};
#pragma unroll
  for (int ks = 0; ks < 2; ++ks) {
    s16x8 ak = *(const s16x8*)&KT[w * 16 + lr][ks * 32 + lg * 8];
    s16x8 bq = *(const s16x8*)&QT[w * 16 + lr][ks * 32 + lg * 8];
    s = __builtin_amdgcn_mfma_f32_16x16x32_bf16(ak, bq, s, 0, 0, 0);
  }
  const float rs = resc[w];
  float a[4];
#pragma unroll
  for (int r = 0; r < 4; ++r) a[r] = s[r] * rs;
  float mx = fmaxf(fmaxf(a[0], a[1]), fmaxf(a[2], a[3]));
  mx = fmaxf(mx, __shfl_xor(mx, 16)); mx = fmaxf(mx, __shfl_xor(mx, 32));
  float sm = 0.f;
#pragma unroll
  for (int r = 0; r < 4; ++r) { a[r] = expf(a[r] - mx); sm += a[r]; }
  sm += __shfl_xor(sm, 16); sm += __shfl_xor(sm, 32);
  const float sinv = 1.0f / sm;
  u16x4 pp;
#pragma unroll
  for (int r = 0; r < 4; ++r) pp[r] = f2us(a[r] * sinv);
  *(u16x4*)&PSb[w][lr][lg * 4] = pp;     // P[d=lr][e=lg*4+r]
  __syncthreads();                   // all S^T reads of QT done -> VM may overwrite
#pragma unroll
  for (int mt = 0; mt < 4; ++mt)
#pragma unroll
    for (int r = 0; r < 4; ++r)
      VM[mt * 16 + lg * 4 + r][w * 16 + lr] = f2us(vacc[mt][r]);   // VM[m][d]
  __syncthreads();                   // VM complete

  const s16x8 zf = (s16x8){0, 0, 0, 0, 0, 0, 0, 0};
  s16x8 pa = zf;
  if (lg < 2) pa = *(const s16x8*)&PSb[w][lr][lg * 8];
#pragma unroll
  for (int mt = 0; mt < 4; ++mt) {
    s16x8 bv = zf;
    if (lg < 2) bv = *(const s16x8*)&VM[mt * 16 + lr][w * 16 + lg * 8];
    f32x4 o = __builtin_amdgcn_mfma_f32_16x16x32_bf16(pa, bv, (f32x4){0.f, 0.f, 0.f, 0.f}, 0, 0, 0);
    u16x4 u;
#pragma unroll
    for (int r = 0; r < 4; ++r) u[r] = f2us(o[r]);
    *(u16x4*)&X1[mt * 16 + lr][w * 16 + lg * 4] = u;
  }
  __syncthreads();

  f32x4 pacc[4];
#pragma unroll
  for (int mt = 0; mt < 4; ++mt) pacc[mt] = (f32x4){0.f, 0.f, 0.f, 0.f};
#pragma unroll
  for (int ks = 0; ks < 2; ++ks) {
    s16x8 bx = *(const s16x8*)&X1[w * 16 + lr][ks * 32 + lg * 8];
#pragma unroll
    for (int mt = 0; mt < 4; ++mt) {
      s16x8 ap = *(const s16x8*)(pwT + (mt * 16 + lr) * 64 + ks * 32 + lg * 8);
      pacc[mt] = __builtin_amdgcn_mfma_f32_16x16x32_bf16(ap, bx, pacc[mt], 0, 0, 0);
    }
  }
#pragma unroll
  for (int mt = 0; mt < 4; ++mt) {
    const float4 bias = *(const float4*)(pb + mt * 16 + lg * 4);
    u16x4 u;
    u[0] = f2us(pacc[mt][0] + bias.x); u[1] = f2us(pacc[mt][1] + bias.y);
    u[2] = f2us(pacc[mt][2] + bias.z); u[3] = f2us(pacc[mt][3] + bias.w);
    *(u16x4*)&X1[w * 16 + lr][mt * 16 + lg * 4] = u;
  }
  __syncthreads();
#pragma unroll
  for (int it = 0; it < 2; ++it) {
    const int id = it * 256 + t;
    const int mm = id >> 3, c8 = (id & 7) * 8;
    *(u16x8*)(xlow + gaddr(nb, mm) + c8) = *(const u16x8*)&X1[mm][c8];
  }
}

// ------- fused depthwise + c2 GEMM + combine + IDCT-W (512 threads) ---------
__global__ __launch_bounds__(512) void k_dwc2i(const u16t* __restrict__ y1,
    u16t* __restrict__ xio, const u16t* __restrict__ xlow,
    const u16t* __restrict__ W2b, const u16t* __restrict__ Mti,
    const float* __restrict__ dwg, const float* __restrict__ coef)
{
  __shared__ __align__(16) char smu[36864];    // OT[256][72] U XT[64][264]
  u16t (*OT)[72]  = (u16t(*)[72])smu;
  u16t (*XT)[264] = (u16t(*)[264])smu;
  __shared__ float dws[64][9];
  const int t = threadIdx.x, w = t >> 6, l = t & 63;
  const int lr = l & 15, lg = l >> 4;
  const int bid = blockIdx.x;
  const int blk = (bid & 7) * 128 + (bid >> 3);   // XCD-aware row swizzle
  const int b = blk >> 8, py = blk & 255;
  const size_t ebase = (size_t)blk * 16384;
  const int pb0 = py * 256;
  for (int e = t; e < 576; e += 512) dws[e / 9][e % 9] = dwg[e];
  __syncthreads();
  // ---- phase A: depthwise 3x3 + gelu + residual -> OT (4 passes) ----
  {
    const int c8 = (t & 7) * 8;
#pragma unroll
    for (int pass = 0; pass < 4; ++pass) {
      const int px = pass * 64 + (t >> 3);
      float acc[8] = {0.f, 0.f, 0.f, 0.f, 0.f, 0.f, 0.f, 0.f};
#pragma unroll
      for (int dy = 0; dy < 3; ++dy) {
        const int ry = py + dy - 1;
        const bool rowok = (unsigned)ry < 256u;
#pragma unroll
        for (int dx = 0; dx < 3; ++dx) {
          const int rx = px + dx - 1;
          u16x8 v = {0, 0, 0, 0, 0, 0, 0, 0};
          if (rowok && (unsigned)rx < 256u)
            v = *(const u16x8*)(y1 + ((size_t)((b * 256 + ry) * 256 + rx)) * 64 + c8);
          const int j = dy * 3 + dx;
#pragma unroll
          for (int r = 0; r < 8; ++r) acc[r] = fmaf(us2f(v[r]), dws[c8 + r][j], acc[r]);
        }
      }
      const u16x8 x = *(const u16x8*)(xio + ebase + (size_t)px * 64 + c8);
      u16x8 o;
#pragma unroll
      for (int r = 0; r < 8; ++r) o[r] = f2us(gelu(acc[r]) + us2f(x[r]));
      *(u16x8*)&OT[px][c8] = o;
    }
  }
  __syncthreads();
  // ---- phase B: c2 GEMM (wave w owns px tile [w*32, w*32+32)) ----
  s16x8 af[4][2];
#pragma unroll
  for (int mt = 0; mt < 4; ++mt)
#pragma unroll
    for (int ks = 0; ks < 2; ++ks)
      af[mt][ks] = *(const s16x8*)(W2b + (mt * 16 + lr) * 64 + ks * 32 + lg * 8);
  f32x4 acc[4][2];
#pragma unroll
  for (int i = 0; i < 4; ++i)
#pragma unroll
    for (int j = 0; j < 2; ++j) acc[i][j] = (f32x4){0.f, 0.f, 0.f, 0.f};
#pragma unroll
  for (int nt = 0; nt < 2; ++nt) {
    const int px = w * 32 + nt * 16 + lr;
#pragma unroll
    for (int ks = 0; ks < 2; ++ks) {
      s16x8 bf = *(const s16x8*)&OT[px][ks * 32 + lg * 8];
#pragma unroll
      for (int mt = 0; mt < 4; ++mt)
        acc[mt][nt] = __builtin_amdgcn_mfma_f32_16x16x32_bf16(af[mt][ks], bf, acc[mt][nt], 0, 0, 0);
    }
  }
  u16x4 cmb[2][4];                   // combined row values, bf16, in regs
#pragma unroll
  for (int nt = 0; nt < 2; ++nt) {
    const int px = w * 32 + nt * 16 + lr;
    const float cf = coef[pb0 + px];
    const size_t gb = ebase + (size_t)px * 64;
#pragma unroll
    for (int mt = 0; mt < 4; ++mt) {
      const int c0 = mt * 16 + lg * 4;
      const u16x4 xd = *(const u16x4*)(xio + gb + c0);      // L1/L2-hot
      const u16x4 xl = *(const u16x4*)(xlow + gb + c0);
      const u16x4 xr = *(const u16x4*)&OT[px][c0];
      u16x4 o;
#pragma unroll
      for (int r = 0; r < 4; ++r) {
        const float xh = gelu(acc[mt][nt][r]) + us2f(xr[r]);
        o[r] = f2us(cf * us2f(xl[r]) + (1.0f - cf) * xh + us2f(xd[r]));
      }
      cmb[nt][mt] = o;
    }
  }
  __syncthreads();                   // ALL OT reads done -> overwrite as XT
#pragma unroll
  for (int nt = 0; nt < 2; ++nt) {
    const int px = w * 32 + nt * 16 + lr;
#pragma unroll
    for (int mt = 0; mt < 4; ++mt) {
      const int c0 = mt * 16 + lg * 4;
#pragma unroll
      for (int r = 0; r < 4; ++r) XT[c0 + r][px] = cmb[nt][mt][r];
    }
  }
  __syncthreads();                   // XT complete
  // ---- phase C: IDCT-W (wave w owns ko tile [w*32, w*32+32)) ----
  f32x4 acc2[4][2];
#pragma unroll
  for (int i = 0; i < 4; ++i)
#pragma unroll
    for (int j = 0; j < 2; ++j) acc2[i][j] = (f32x4){0.f, 0.f, 0.f, 0.f};
  const u16t* mrow = Mti + (size_t)(w * 32 + lr) * 256 + lg * 8;
  for (int ks = 0; ks < 8; ++ks) {
    s16x8 afr[4];
#pragma unroll
    for (int i = 0; i < 4; ++i)
      afr[i] = *(const s16x8*)&XT[i * 16 + lr][ks * 32 + lg * 8];
#pragma unroll
    for (int j = 0; j < 2; ++j) {
      s16x8 bf = *(const s16x8*)(mrow + ks * 32 + j * 4096);
#pragma unroll
      for (int i = 0; i < 4; ++i)
        acc2[i][j] = __builtin_amdgcn_mfma_f32_16x16x32_bf16(afr[i], bf, acc2[i][j], 0, 0, 0);
    }
  }
  __syncthreads();                   // XT reads done -> reuse buffer as OT
#pragma unroll
  for (int j = 0; j < 2; ++j)
#pragma unroll
    for (int i = 0; i < 4; ++i) {
      u16x4 u;
#pragma unroll
      for (int r = 0; r < 4; ++r) u[r] = f2us(acc2[i][j][r]);
      *(u16x4*)&OT[w * 32 + j * 16 + lr][i * 16 + lg * 4] = u;
    }
  __syncthreads();
#pragma unroll
  for (int it = 0; it < 4; ++it) {
    const int id = it * 512 + t;
    const int ko = id >> 3, c8 = (id & 7) * 8;
    *(u16x8*)(xio + ebase + (size_t)ko * 64 + c8) = *(const u16x8*)&OT[ko][c8];
  }
}

// ----------------------------------------------------------------------------
extern "C" void kernel_launch(void* const* d_in, const int* in_sizes, int n_in,
                              void* d_out, int out_size, void* d_ws, size_t ws_size,
                              hipStream_t stream) {
  const float* x_input = (const float*)d_in[0];
  const float* Wq      = (const float*)d_in[1];
  const float* Wk      = (const float*)d_in[2];
  const float* Wv      = (const float*)d_in[3];
  const float* resc    = (const float*)d_in[4];
  const float* proj_w  = (const float*)d_in[5];
  const float* proj_b  = (const float*)d_in[6];
  const float* c1a_w   = (const float*)d_in[7];
  const float* c1b_w   = (const float*)d_in[8];
  const float* c2_w    = (const float*)d_in[9];
  const float* coef    = (const float*)d_in[10];
  float* out = (float*)d_out;

  char* ws = (char*)d_ws;
  u16t* A   = (u16t*)ws;                       // 33.5 MB
  u16t* Bb  = (u16t*)(ws + 33554432);          // 33.5 MB
  u16t* Mtf = (u16t*)(ws + 67108864);
  u16t* Mti = Mtf + 65536;
  u16t* WqT = Mti + 65536;
  u16t* WkT = WqT + 4096;
  u16t* WvT = WkT + 4096;
  u16t* pwT = WvT + 4096;
  u16t* W1b = pwT + 4096;
  u16t* W2b = W1b + 4096;
  u16t* xlow = (u16t*)d_out;                   // bf16, first half of d_out

  k_init<<<dim3(257), dim3(256), 0, stream>>>(Mtf, Mti, WqT, WkT, WvT, pwT, W1b, W2b,
                                              Wq, Wk, Wv, proj_w, c1a_w, c2_w);
  // DCT along W: x -> A
  k_tmfma<false, true><<<dim3(1024), dim3(512), 0, stream>>>(x_input, A, Mtf, 16384, 64);
  // fused DCT-H + conv1: A -> Bb (xdct), A (y1, in place)
  k_dcthc1<<<dim3(1024), dim3(512), 0, stream>>>(A, Bb, A, Mtf, W1b);
  // attention branch: xdct -> x_low
  k_attn<<<dim3(4096), dim3(256), 0, stream>>>(Bb, xlow, WqT, WkT, WvT, pwT, resc, proj_b);
  // fused depthwise + c2 + combine + IDCT-W: (A=y1, Bb=xdct, xlow) -> Bb in place
  k_dwc2i<<<dim3(1024), dim3(512), 0, stream>>>(A, Bb, xlow, W2b, Mti, c1b_w, coef);
  // IDCT along H: Bb -> out (f32, final NHWC)
  k_tmfma<true, false><<<dim3(1024), dim3(512), 0, stream>>>(Bb, out, Mti, 64, 16384);
}

// Round 18
// 204.450 us; speedup vs baseline: 1.0541x; 1.0204x over previous
//
#include <hip/hip_runtime.h>

#define DI __device__ __forceinline__

typedef unsigned short u16t;
typedef u16t u16x4 __attribute__((ext_vector_type(4)));
typedef u16t u16x8 __attribute__((ext_vector_type(8)));
typedef short s16x8 __attribute__((ext_vector_type(8)));   // bf16 MFMA A/B frag
typedef float f32x4 __attribute__((ext_vector_type(4)));   // MFMA C/D frag

static constexpr int PLANE = 256 * 256 * 64;
static constexpr double PI = 3.14159265358979323846264338327950288;

DI float us2f(u16t u) {
  union { unsigned int i; float f; } v; v.i = ((unsigned int)u) << 16; return v.f;
}
DI u16t f2us(float f) {            // f32 -> bf16, RNE
  union { float f; unsigned int i; } v; v.f = f;
  unsigned int r = v.i + 0x7FFFu + ((v.i >> 16) & 1u);
  return (u16t)(r >> 16);
}
// fast gelu: x*sigmoid(1.59577x + 0.0713548x^3); |err| <= ~3e-3 abs.
DI float gelu(float x) {
  const float t = fmaf(0.0713548162726f * x * x, x, 1.5957691216057308f * x);
  const float e = __expf(-t);
  return x * __builtin_amdgcn_rcpf(1.0f + e);
}

// ------------- init: bf16 transform matrices + bf16 weights -----------------
__global__ void k_init(u16t* __restrict__ Mtf, u16t* __restrict__ Mti,
                       u16t* __restrict__ WqT, u16t* __restrict__ WkT,
                       u16t* __restrict__ WvT, u16t* __restrict__ pwT,
                       u16t* __restrict__ W1b, u16t* __restrict__ W2b,
                       const float* __restrict__ Wq, const float* __restrict__ Wk,
                       const float* __restrict__ Wv, const float* __restrict__ pw,
                       const float* __restrict__ c1a, const float* __restrict__ c2w)
{
  const int blk = blockIdx.x, t = threadIdx.x;
  if (blk < 256) {
    const int ko = blk, n = t;
    double af = PI * (2.0 * n + 1.0) * (double)ko / 512.0;
    Mtf[ko * 256 + n] = f2us((float)(2.0 * cos(af)));
    double wn = (n == 0) ? 0.5 : 1.0;
    double ai = PI * (2.0 * ko + 1.0) * (double)n / 512.0;
    Mti[ko * 256 + n] = f2us((float)(wn * cos(ai) / 256.0));
  } else {
    for (int i = 0; i < 16; ++i) {
      const int e = i * 256 + t;
      const int d = e >> 6, c = e & 63;
      WqT[e] = f2us(Wq[c * 64 + d]);
      WkT[e] = f2us(Wk[c * 64 + d]);
      WvT[e] = f2us(Wv[c * 64 + d]);
      pwT[e] = f2us(pw[c * 64 + d]);
      W1b[e] = f2us(c1a[e]);
      W2b[e] = f2us(c2w[e]);
    }
  }
}

// ---------------- 1-D transform, MFMA, 512 threads (8 waves) ----------------
template<bool INBF, bool OUTBF>
__global__ __launch_bounds__(512) void k_tmfma(const void* __restrict__ inv,
    void* __restrict__ outv, const u16t* __restrict__ Mt,
    const int s_other, const int s_row)
{
  __shared__ __align__(16) char sm[36864];     // XT[64][264] U OT[256][72]
  u16t (*XT)[264] = (u16t(*)[264])sm;
  u16t (*OT)[72]  = (u16t(*)[72])sm;
  const int t = threadIdx.x;
  const int b = blockIdx.x >> 8, other = blockIdx.x & 255;
  const size_t base = (size_t)b * PLANE + (size_t)other * (size_t)s_other;
  if constexpr (INBF) {
#pragma unroll
    for (int q = 0; q < 4; ++q) {
      const int id = q * 512 + t;
      const int n = id >> 3, c8 = (id & 7) * 8;
      u16x8 u = *(const u16x8*)((const u16t*)inv + base + (size_t)n * (size_t)s_row + c8);
#pragma unroll
      for (int j = 0; j < 8; ++j) XT[c8 + j][n] = u[j];
    }
  } else {
#pragma unroll
    for (int q = 0; q < 8; ++q) {
      const int id = q * 512 + t;
      const int n = id >> 4, c4 = (id & 15) * 4;
      float4 v = *(const float4*)((const float*)inv + base + (size_t)n * (size_t)s_row + c4);
      XT[c4 + 0][n] = f2us(v.x); XT[c4 + 1][n] = f2us(v.y);
      XT[c4 + 2][n] = f2us(v.z); XT[c4 + 3][n] = f2us(v.w);
    }
  }
  __syncthreads();
  const int w = t >> 6, l = t & 63;
  const int lr = l & 15, lg = l >> 4;
  f32x4 acc[4][2];
#pragma unroll
  for (int i = 0; i < 4; ++i)
#pragma unroll
    for (int j = 0; j < 2; ++j) acc[i][j] = (f32x4){0.f, 0.f, 0.f, 0.f};

  const u16t* mrow = Mt + (size_t)(w * 32 + lr) * 256 + lg * 8;
  s16x8 bnxt[2];
#pragma unroll
  for (int j = 0; j < 2; ++j) bnxt[j] = *(const s16x8*)(mrow + j * 4096);
  for (int ks = 0; ks < 8; ++ks) {
    s16x8 bcur[2];
#pragma unroll
    for (int j = 0; j < 2; ++j) bcur[j] = bnxt[j];
    if (ks < 7) {
#pragma unroll
      for (int j = 0; j < 2; ++j) bnxt[j] = *(const s16x8*)(mrow + (ks + 1) * 32 + j * 4096);
    }
    s16x8 afr[4];
#pragma unroll
    for (int i = 0; i < 4; ++i)
      afr[i] = *(const s16x8*)&XT[i * 16 + lr][ks * 32 + lg * 8];
#pragma unroll
    for (int i = 0; i < 4; ++i)
#pragma unroll
      for (int j = 0; j < 2; ++j)
        acc[i][j] = __builtin_amdgcn_mfma_f32_16x16x32_bf16(afr[i], bcur[j], acc[i][j], 0, 0, 0);
  }
  if constexpr (OUTBF) {
    __syncthreads();                 // all XT reads done; reuse LDS as OT
#pragma unroll
    for (int j = 0; j < 2; ++j)
#pragma unroll
      for (int i = 0; i < 4; ++i) {
        u16x4 u;
#pragma unroll
        for (int r = 0; r < 4; ++r) u[r] = f2us(acc[i][j][r]);
        *(u16x4*)&OT[w * 32 + j * 16 + lr][i * 16 + lg * 4] = u;
      }
    __syncthreads();
#pragma unroll
    for (int it = 0; it < 4; ++it) {
      const int id = it * 512 + t;
      const int ko = id >> 3, c8 = (id & 7) * 8;
      *(u16x8*)((u16t*)outv + base + (size_t)ko * (size_t)s_row + c8) =
          *(const u16x8*)&OT[ko][c8];
    }
  } else {
#pragma unroll
    for (int j = 0; j < 2; ++j)
#pragma unroll
      for (int i = 0; i < 4; ++i) {
        const size_t o = base + (size_t)(w * 32 + j * 16 + lr) * (size_t)s_row + i * 16 + lg * 4;
        *(f32x4*)((float*)outv + o) = acc[i][j];
      }
  }
}

// ------- fused DCT-H + conv1: 512 threads, single aliased LDS buffer --------
__global__ __launch_bounds__(512) void k_dcthc1(const u16t* __restrict__ inv,
    u16t* __restrict__ xdct, u16t* __restrict__ y1out,
    const u16t* __restrict__ Mt, const u16t* __restrict__ W1b)
{
  __shared__ __align__(16) char sm[36864];     // XT[64][264] U OT[256][72] U Y1
  u16t (*XT)[264] = (u16t(*)[264])sm;
  u16t (*OT)[72]  = (u16t(*)[72])sm;
  const int t = threadIdx.x;
  const int b = blockIdx.x >> 8, kw = blockIdx.x & 255;
  const size_t base = (size_t)b * PLANE + (size_t)kw * 64;
#pragma unroll
  for (int q = 0; q < 4; ++q) {
    const int id = q * 512 + t;
    const int n = id >> 3, c8 = (id & 7) * 8;
    u16x8 u = *(const u16x8*)(inv + base + (size_t)n * 16384 + c8);
#pragma unroll
    for (int j = 0; j < 8; ++j) XT[c8 + j][n] = u[j];
  }
  __syncthreads();
  const int w = t >> 6, l = t & 63;
  const int lr = l & 15, lg = l >> 4;
  f32x4 acc[4][2];
#pragma unroll
  for (int i = 0; i < 4; ++i)
#pragma unroll
    for (int j = 0; j < 2; ++j) acc[i][j] = (f32x4){0.f, 0.f, 0.f, 0.f};
  const u16t* mrow = Mt + (size_t)(w * 32 + lr) * 256 + lg * 8;
  for (int ks = 0; ks < 8; ++ks) {
    s16x8 afr[4];
#pragma unroll
    for (int i = 0; i < 4; ++i)
      afr[i] = *(const s16x8*)&XT[i * 16 + lr][ks * 32 + lg * 8];
#pragma unroll
    for (int j = 0; j < 2; ++j) {
      s16x8 bf = *(const s16x8*)(mrow + ks * 32 + j * 4096);
#pragma unroll
      for (int i = 0; i < 4; ++i)
        acc[i][j] = __builtin_amdgcn_mfma_f32_16x16x32_bf16(afr[i], bf, acc[i][j], 0, 0, 0);
    }
  }
  __syncthreads();                   // XT reads done -> reuse buffer as OT
#pragma unroll
  for (int j = 0; j < 2; ++j)
#pragma unroll
    for (int i = 0; i < 4; ++i) {
      u16x4 u;
#pragma unroll
      for (int r = 0; r < 4; ++r) u[r] = f2us(acc[i][j][r]);
      *(u16x4*)&OT[w * 32 + j * 16 + lr][i * 16 + lg * 4] = u;
    }
  __syncthreads();                   // OT (xdct tile) complete
#pragma unroll
  for (int it = 0; it < 4; ++it) {
    const int id = it * 512 + t;
    const int ko = id >> 3, c8 = (id & 7) * 8;
    *(u16x8*)(xdct + base + (size_t)ko * 16384 + c8) = *(const u16x8*)&OT[ko][c8];
  }
  s16x8 af2[4][2];
#pragma unroll
  for (int mt = 0; mt < 4; ++mt)
#pragma unroll
    for (int ks = 0; ks < 2; ++ks)
      af2[mt][ks] = *(const s16x8*)(W1b + (mt * 16 + lr) * 64 + ks * 32 + lg * 8);
  f32x4 acc2[4][2];
#pragma unroll
  for (int i = 0; i < 4; ++i)
#pragma unroll
    for (int j = 0; j < 2; ++j) acc2[i][j] = (f32x4){0.f, 0.f, 0.f, 0.f};
#pragma unroll
  for (int nt = 0; nt < 2; ++nt) {
    const int px = w * 32 + nt * 16 + lr;
#pragma unroll
    for (int ks = 0; ks < 2; ++ks) {
      s16x8 bf = *(const s16x8*)&OT[px][ks * 32 + lg * 8];
#pragma unroll
      for (int mt = 0; mt < 4; ++mt)
        acc2[mt][nt] = __builtin_amdgcn_mfma_f32_16x16x32_bf16(af2[mt][ks], bf, acc2[mt][nt], 0, 0, 0);
    }
  }
  __syncthreads();                   // OT reads done -> reuse buffer as Y1
#pragma unroll
  for (int mt = 0; mt < 4; ++mt)
#pragma unroll
    for (int nt = 0; nt < 2; ++nt) {
      const int px = w * 32 + nt * 16 + lr;
      u16x4 u;
#pragma unroll
      for (int r = 0; r < 4; ++r) u[r] = f2us(gelu(acc2[mt][nt][r]));
      *(u16x4*)&OT[px][mt * 16 + lg * 4] = u;
    }
  __syncthreads();
#pragma unroll
  for (int it = 0; it < 4; ++it) {
    const int id = it * 512 + t;
    const int kh = id >> 3, c8 = (id & 7) * 8;
    *(u16x8*)(y1out + base + (size_t)kh * 16384 + c8) = *(const u16x8*)&OT[kh][c8];
  }
}

// ---------------- attention branch: 30 KB LDS, 5 barriers -------------------
DI size_t gaddr(int nb, int mm) {
  const int b = nb >> 10, r = nb & 1023, bh = r >> 5, bw = r & 31;
  const int i = mm >> 3, j = mm & 7;
  return ((size_t)((b * 256 + bh * 8 + i) * 256 + bw * 8 + j)) * 64;
}

__global__ __launch_bounds__(256, 5) void k_attn(const u16t* __restrict__ xdct,
    u16t* __restrict__ xlow, const u16t* __restrict__ WqT,
    const u16t* __restrict__ WkT, const u16t* __restrict__ WvT,
    const u16t* __restrict__ pwT, const float* __restrict__ resc,
    const float* __restrict__ pb)
{
  __shared__ __align__(16) u16t Xs[64][72], QT[64][72], KT[64][72];
  __shared__ __align__(16) u16t PSb[4][16][24];
  u16t (*X1)[72] = Xs;   // alias: afr (only Xs reads) precede post-PSb barrier,
                         // which precedes all X1 writes -> safe without extra fence
  u16t (*VM)[72] = QT;   // alias: QT dead after S^T; post-PSb barrier fences it
  const int t = threadIdx.x, w = t >> 6, l = t & 63;
  const int lr = l & 15, lg = l >> 4;
  const int nb = blockIdx.x;
#pragma unroll
  for (int q = 0; q < 2; ++q) {
    const int id = q * 256 + t, px = id >> 3, c8 = (id & 7) * 8;
    *(u16x8*)&Xs[px][c8] = *(const u16x8*)(xdct + gaddr(nb, px) + c8);
  }
  __syncthreads();                   // barrier 1: Xs staged
  s16x8 afr[4][2];
#pragma unroll
  for (int mt = 0; mt < 4; ++mt)
#pragma unroll
    for (int ks = 0; ks < 2; ++ks)
      afr[mt][ks] = *(const s16x8*)&Xs[mt * 16 + lr][ks * 32 + lg * 8];
  // (no barrier: Xs first overwritten after barrier 2, which all waves'
  //  afr reads precede in program order)

  auto qkv = [&](const u16t* __restrict__ WT, u16t (&DST)[64][72]) {
    f32x4 acc[4];
#pragma unroll
    for (int mt = 0; mt < 4; ++mt) acc[mt] = (f32x4){0.f, 0.f, 0.f, 0.f};
#pragma unroll
    for (int ks = 0; ks < 2; ++ks) {
      s16x8 bf = *(const s16x8*)(WT + (w * 16 + lr) * 64 + ks * 32 + lg * 8);
#pragma unroll
      for (int mt = 0; mt < 4; ++mt)
        acc[mt] = __builtin_amdgcn_mfma_f32_16x16x32_bf16(afr[mt][ks], bf, acc[mt], 0, 0, 0);
    }
    float ss = 0.f;
#pragma unroll
    for (int mt = 0; mt < 4; ++mt)
#pragma unroll
      for (int r = 0; r < 4; ++r) ss = fmaf(acc[mt][r], acc[mt][r], ss);
    ss += __shfl_xor(ss, 16); ss += __shfl_xor(ss, 32);
    const float inv = 1.0f / fmaxf(sqrtf(ss), 1e-12f);
#pragma unroll
    for (int mt = 0; mt < 4; ++mt) {
      u16x4 u;
#pragma unroll
      for (int r = 0; r < 4; ++r) u[r] = f2us(acc[mt][r] * inv);
      *(u16x4*)&DST[w * 16 + lr][mt * 16 + lg * 4] = u;
    }
  };
  qkv(WqT, QT);
  qkv(WkT, KT);
  f32x4 vacc[4];
#pragma unroll
  for (int mt = 0; mt < 4; ++mt) vacc[mt] = (f32x4){0.f, 0.f, 0.f, 0.f};
#pragma unroll
  for (int ks = 0; ks < 2; ++ks) {
    s16x8 bf = *(const s16x8*)(WvT + (w * 16 + lr) * 64 + ks * 32 + lg * 8);
#pragma unroll
    for (int mt = 0; mt < 4; ++mt)
      vacc[mt] = __builtin_amdgcn_mfma_f32_16x16x32_bf16(afr[mt][ks], bf, vacc[mt], 0, 0, 0);
  }

  // S^T reads QT/KT rows written by this wave (w-private) — no barrier needed
  f32x4 s = (f32x4){0.f, 0.f, 0.f, 0.f};
#pragma unroll
  for (int ks = 0; ks < 2; ++ks) {
    s16x8 ak = *(const s16x8*)&KT[w * 16 + lr][ks * 32 + lg * 8];
    s16x8 bq = *(const s16x8*)&QT[w * 16 + lr][ks * 32 + lg * 8];
    s = __builtin_amdgcn_mfma_f32_16x16x32_bf16(ak, bq, s, 0, 0, 0);
  }
  const float rs = resc[w];
  float a[4];
#pragma unroll
  for (int r = 0; r < 4; ++r) a[r] = s[r] * rs;
  float mx = fmaxf(fmaxf(a[0], a[1]), fmaxf(a[2], a[3]));
  mx = fmaxf(mx, __shfl_xor(mx, 16)); mx = fmaxf(mx, __shfl_xor(mx, 32));
  float sm = 0.f;
#pragma unroll
  for (int r = 0; r < 4; ++r) { a[r] = expf(a[r] - mx); sm += a[r]; }
  sm += __shfl_xor(sm, 16); sm += __shfl_xor(sm, 32);
  const float sinv = 1.0f / sm;
  u16x4 pp;
#pragma unroll
  for (int r = 0; r < 4; ++r) pp[r] = f2us(a[r] * sinv);
  *(u16x4*)&PSb[w][lr][lg * 4] = pp;     // P[d=lr][e=lg*4+r]  (wave-private)
  __syncthreads();                   // barrier 2: all QT reads done everywhere
  // VM overwrite of QT region; PV below reads ONLY this wave's VM columns
  // (cols w*16..w*16+15) -> same-wave LDS RAW, compiler lgkmcnt suffices.
#pragma unroll
  for (int mt = 0; mt < 4; ++mt)
#pragma unroll
    for (int r = 0; r < 4; ++r)
      VM[mt * 16 + lg * 4 + r][w * 16 + lr] = f2us(vacc[mt][r]);   // VM[m][d]

  const s16x8 zf = (s16x8){0, 0, 0, 0, 0, 0, 0, 0};
  s16x8 pa = zf;
  if (lg < 2) pa = *(const s16x8*)&PSb[w][lr][lg * 8];
#pragma unroll
  for (int mt = 0; mt < 4; ++mt) {
    s16x8 bv = zf;
    if (lg < 2) bv = *(const s16x8*)&VM[mt * 16 + lr][w * 16 + lg * 8];
    f32x4 o = __builtin_amdgcn_mfma_f32_16x16x32_bf16(pa, bv, (f32x4){0.f, 0.f, 0.f, 0.f}, 0, 0, 0);
    u16x4 u;
#pragma unroll
    for (int r = 0; r < 4; ++r) u[r] = f2us(o[r]);
    *(u16x4*)&X1[mt * 16 + lr][w * 16 + lg * 4] = u;   // cols w-private
  }
  __syncthreads();                   // barrier 3: X1 complete (proj is cross-wave)

  f32x4 pacc[4];
#pragma unroll
  for (int mt = 0; mt < 4; ++mt) pacc[mt] = (f32x4){0.f, 0.f, 0.f, 0.f};
#pragma unroll
  for (int ks = 0; ks < 2; ++ks) {
    s16x8 bx = *(const s16x8*)&X1[w * 16 + lr][ks * 32 + lg * 8];
#pragma unroll
    for (int mt = 0; mt < 4; ++mt) {
      s16x8 ap = *(const s16x8*)(pwT + (mt * 16 + lr) * 64 + ks * 32 + lg * 8);
      pacc[mt] = __builtin_amdgcn_mfma_f32_16x16x32_bf16(ap, bx, pacc[mt], 0, 0, 0);
    }
  }
  __syncthreads();                   // barrier 4: all X1 reads done before overwrite
#pragma unroll
  for (int mt = 0; mt < 4; ++mt) {
    const float4 bias = *(const float4*)(pb + mt * 16 + lg * 4);
    u16x4 u;
    u[0] = f2us(pacc[mt][0] + bias.x); u[1] = f2us(pacc[mt][1] + bias.y);
    u[2] = f2us(pacc[mt][2] + bias.z); u[3] = f2us(pacc[mt][3] + bias.w);
    *(u16x4*)&X1[w * 16 + lr][mt * 16 + lg * 4] = u;
  }
  __syncthreads();                   // barrier 5: output staged
#pragma unroll
  for (int it = 0; it < 2; ++it) {
    const int id = it * 256 + t;
    const int mm = id >> 3, c8 = (id & 7) * 8;
    *(u16x8*)(xlow + gaddr(nb, mm) + c8) = *(const u16x8*)&X1[mm][c8];
  }
}

// ------- fused depthwise + c2 GEMM + combine + IDCT-W (512 threads) ---------
__global__ __launch_bounds__(512) void k_dwc2i(const u16t* __restrict__ y1,
    u16t* __restrict__ xio, const u16t* __restrict__ xlow,
    const u16t* __restrict__ W2b, const u16t* __restrict__ Mti,
    const float* __restrict__ dwg, const float* __restrict__ coef)
{
  __shared__ __align__(16) char smu[36864];    // OT[256][72] U XT[64][264]
  u16t (*OT)[72]  = (u16t(*)[72])smu;
  u16t (*XT)[264] = (u16t(*)[264])smu;
  __shared__ float dws[64][9];
  const int t = threadIdx.x, w = t >> 6, l = t & 63;
  const int lr = l & 15, lg = l >> 4;
  const int bid = blockIdx.x;
  const int blk = (bid & 7) * 128 + (bid >> 3);   // XCD-aware row swizzle
  const int b = blk >> 8, py = blk & 255;
  const size_t ebase = (size_t)blk * 16384;
  const int pb0 = py * 256;
  for (int e = t; e < 576; e += 512) dws[e / 9][e % 9] = dwg[e];
  __syncthreads();
  // ---- phase A: depthwise 3x3 + gelu + residual -> OT (4 passes) ----
  {
    const int c8 = (t & 7) * 8;
#pragma unroll
    for (int pass = 0; pass < 4; ++pass) {
      const int px = pass * 64 + (t >> 3);
      float acc[8] = {0.f, 0.f, 0.f, 0.f, 0.f, 0.f, 0.f, 0.f};
#pragma unroll
      for (int dy = 0; dy < 3; ++dy) {
        const int ry = py + dy - 1;
        const bool rowok = (unsigned)ry < 256u;
#pragma unroll
        for (int dx = 0; dx < 3; ++dx) {
          const int rx = px + dx - 1;
          u16x8 v = {0, 0, 0, 0, 0, 0, 0, 0};
          if (rowok && (unsigned)rx < 256u)
            v = *(const u16x8*)(y1 + ((size_t)((b * 256 + ry) * 256 + rx)) * 64 + c8);
          const int j = dy * 3 + dx;
#pragma unroll
          for (int r = 0; r < 8; ++r) acc[r] = fmaf(us2f(v[r]), dws[c8 + r][j], acc[r]);
        }
      }
      const u16x8 x = *(const u16x8*)(xio + ebase + (size_t)px * 64 + c8);
      u16x8 o;
#pragma unroll
      for (int r = 0; r < 8; ++r) o[r] = f2us(gelu(acc[r]) + us2f(x[r]));
      *(u16x8*)&OT[px][c8] = o;
    }
  }
  __syncthreads();
  // ---- phase B: c2 GEMM (wave w owns px tile [w*32, w*32+32)) ----
  s16x8 af[4][2];
#pragma unroll
  for (int mt = 0; mt < 4; ++mt)
#pragma unroll
    for (int ks = 0; ks < 2; ++ks)
      af[mt][ks] = *(const s16x8*)(W2b + (mt * 16 + lr) * 64 + ks * 32 + lg * 8);
  f32x4 acc[4][2];
#pragma unroll
  for (int i = 0; i < 4; ++i)
#pragma unroll
    for (int j = 0; j < 2; ++j) acc[i][j] = (f32x4){0.f, 0.f, 0.f, 0.f};
#pragma unroll
  for (int nt = 0; nt < 2; ++nt) {
    const int px = w * 32 + nt * 16 + lr;
#pragma unroll
    for (int ks = 0; ks < 2; ++ks) {
      s16x8 bf = *(const s16x8*)&OT[px][ks * 32 + lg * 8];
#pragma unroll
      for (int mt = 0; mt < 4; ++mt)
        acc[mt][nt] = __builtin_amdgcn_mfma_f32_16x16x32_bf16(af[mt][ks], bf, acc[mt][nt], 0, 0, 0);
    }
  }
  u16x4 cmb[2][4];                   // combined row values, bf16, in regs
#pragma unroll
  for (int nt = 0; nt < 2; ++nt) {
    const int px = w * 32 + nt * 16 + lr;
    const float cf = coef[pb0 + px];
    const size_t gb = ebase + (size_t)px * 64;
#pragma unroll
    for (int mt = 0; mt < 4; ++mt) {
      const int c0 = mt * 16 + lg * 4;
      const u16x4 xd = *(const u16x4*)(xio + gb + c0);      // L1/L2-hot
      const u16x4 xl = *(const u16x4*)(xlow + gb + c0);
      const u16x4 xr = *(const u16x4*)&OT[px][c0];
      u16x4 o;
#pragma unroll
      for (int r = 0; r < 4; ++r) {
        const float xh = gelu(acc[mt][nt][r]) + us2f(xr[r]);
        o[r] = f2us(cf * us2f(xl[r]) + (1.0f - cf) * xh + us2f(xd[r]));
      }
      cmb[nt][mt] = o;
    }
  }
  __syncthreads();                   // ALL OT reads done -> overwrite as XT
#pragma unroll
  for (int nt = 0; nt < 2; ++nt) {
    const int px = w * 32 + nt * 16 + lr;
#pragma unroll
    for (int mt = 0; mt < 4; ++mt) {
      const int c0 = mt * 16 + lg * 4;
#pragma unroll
      for (int r = 0; r < 4; ++r) XT[c0 + r][px] = cmb[nt][mt][r];
    }
  }
  __syncthreads();                   // XT complete
  // ---- phase C: IDCT-W (wave w owns ko tile [w*32, w*32+32)) ----
  f32x4 acc2[4][2];
#pragma unroll
  for (int i = 0; i < 4; ++i)
#pragma unroll
    for (int j = 0; j < 2; ++j) acc2[i][j] = (f32x4){0.f, 0.f, 0.f, 0.f};
  const u16t* mrow = Mti + (size_t)(w * 32 + lr) * 256 + lg * 8;
  for (int ks = 0; ks < 8; ++ks) {
    s16x8 afr[4];
#pragma unroll
    for (int i = 0; i < 4; ++i)
      afr[i] = *(const s16x8*)&XT[i * 16 + lr][ks * 32 + lg * 8];
#pragma unroll
    for (int j = 0; j < 2; ++j) {
      s16x8 bf = *(const s16x8*)(mrow + ks * 32 + j * 4096);
#pragma unroll
      for (int i = 0; i < 4; ++i)
        acc2[i][j] = __builtin_amdgcn_mfma_f32_16x16x32_bf16(afr[i], bf, acc2[i][j], 0, 0, 0);
    }
  }
  __syncthreads();                   // XT reads done -> reuse buffer as OT
#pragma unroll
  for (int j = 0; j < 2; ++j)
#pragma unroll
    for (int i = 0; i < 4; ++i) {
      u16x4 u;
#pragma unroll
      for (int r = 0; r < 4; ++r) u[r] = f2us(acc2[i][j][r]);
      *(u16x4*)&OT[w * 32 + j * 16 + lr][i * 16 + lg * 4] = u;
    }
  __syncthreads();
#pragma unroll
  for (int it = 0; it < 4; ++it) {
    const int id = it * 512 + t;
    const int ko = id >> 3, c8 = (id & 7) * 8;
    *(u16x8*)(xio + ebase + (size_t)ko * 64 + c8) = *(const u16x8*)&OT[ko][c8];
  }
}

// ----------------------------------------------------------------------------
extern "C" void kernel_launch(void* const* d_in, const int* in_sizes, int n_in,
                              void* d_out, int out_size, void* d_ws, size_t ws_size,
                              hipStream_t stream) {
  const float* x_input = (const float*)d_in[0];
  const float* Wq      = (const float*)d_in[1];
  const float* Wk      = (const float*)d_in[2];
  const float* Wv      = (const float*)d_in[3];
  const float* resc    = (const float*)d_in[4];
  const float* proj_w  = (const float*)d_in[5];
  const float* proj_b  = (const float*)d_in[6];
  const float* c1a_w   = (const float*)d_in[7];
  const float* c1b_w   = (const float*)d_in[8];
  const float* c2_w    = (const float*)d_in[9];
  const float* coef    = (const float*)d_in[10];
  float* out = (float*)d_out;

  char* ws = (char*)d_ws;
  u16t* A   = (u16t*)ws;                       // 33.5 MB
  u16t* Bb  = (u16t*)(ws + 33554432);          // 33.5 MB
  u16t* Mtf = (u16t*)(ws + 67108864);
  u16t* Mti = Mtf + 65536;
  u16t* WqT = Mti + 65536;
  u16t* WkT = WqT + 4096;
  u16t* WvT = WkT + 4096;
  u16t* pwT = WvT + 4096;
  u16t* W1b = pwT + 4096;
  u16t* W2b = W1b + 4096;
  u16t* xlow = (u16t*)d_out;                   // bf16, first half of d_out

  k_init<<<dim3(257), dim3(256), 0, stream>>>(Mtf, Mti, WqT, WkT, WvT, pwT, W1b, W2b,
                                              Wq, Wk, Wv, proj_w, c1a_w, c2_w);
  // DCT along W: x -> A
  k_tmfma<false, true><<<dim3(1024), dim3(512), 0, stream>>>(x_input, A, Mtf, 16384, 64);
  // fused DCT-H + conv1: A -> Bb (xdct), A (y1, in place)
  k_dcthc1<<<dim3(1024), dim3(512), 0, stream>>>(A, Bb, A, Mtf, W1b);
  // attention branch: xdct -> x_low
  k_attn<<<dim3(4096), dim3(256), 0, stream>>>(Bb, xlow, WqT, WkT, WvT, pwT, resc, proj_b);
  // fused depthwise + c2 + combine + IDCT-W: (A=y1, Bb=xdct, xlow) -> Bb in place
  k_dwc2i<<<dim3(1024), dim3(512), 0, stream>>>(A, Bb, xlow, W2b, Mti, c1b_w, coef);
  // IDCT along H: Bb -> out (f32, final NHWC)
  k_tmfma<true, false><<<dim3(1024), dim3(512), 0, stream>>>(Bb, out, Mti, 64, 16384);
}